// Round 8
// baseline (95.305 us; speedup 1.0000x reference)
//
#include <hip/hip_runtime.h>
#include <math.h>

#define BB 4
#define TT 1024
#define EE 512
#define HH 8
#define DD 64
#define BT (BB * TT)   // 4096

typedef _Float16 f16;
typedef __attribute__((ext_vector_type(8))) _Float16 f16x8;
typedef __attribute__((ext_vector_type(4))) float f32x4;

// ---------------------------------------------------------------------------
// Prep: y=0..3 weight planes (transposed f16), y=4/5 split q/kv into hi+lo
// f16 planes [BT][512]. Grid (1024, 6).
// ---------------------------------------------------------------------------
__global__ __launch_bounds__(256) void prep_k(
    const float* __restrict__ q, const float* __restrict__ kv,
    const float* __restrict__ Wq, const float* __restrict__ Wk,
    const float* __restrict__ Wv, const float* __restrict__ Wo,
    f16* __restrict__ wqh, f16* __restrict__ wql,
    f16* __restrict__ wkh, f16* __restrict__ wkl,
    f16* __restrict__ wvh, f16* __restrict__ woh,
    f16* __restrict__ qAhi, f16* __restrict__ qAlo,
    f16* __restrict__ kvAhi, f16* __restrict__ kvAlo) {
    const int t = threadIdx.x;
    const int y = blockIdx.y;
    if (y < 4) {
        int idx = blockIdx.x * 256 + t;        // 512*512 elems
        int k = idx & (EE - 1);
        int n = idx >> 9;
        if (y == 0) {
            float v = Wq[k * EE + n] * 512.0f; // fold dk*D scale (exact pow2)
            f16 hi = (f16)v;
            wqh[n * EE + k] = hi;
            wql[n * EE + k] = (f16)(v - (float)hi);
        } else if (y == 1) {
            int d = n >> 3, h = n & 7;
            int sn = (((DD - d) & (DD - 1)) << 3) | h;  // K'[.,d]=K[.,(D-d)%D]
            float v = Wk[k * EE + sn];
            f16 hi = (f16)v;
            wkh[n * EE + k] = hi;
            wkl[n * EE + k] = (f16)(v - (float)hi);
        } else if (y == 2) {
            wvh[n * EE + k] = (f16)Wv[k * EE + n];
        } else {
            woh[n * EE + k] = (f16)Wo[k * EE + n];
        }
    } else {
        const float* src = (y == 4) ? q : kv;
        f16* dh = (y == 4) ? qAhi : kvAhi;
        f16* dl = (y == 4) ? qAlo : kvAlo;
        int base = (blockIdx.x * 256 + t) * 8;
        float4 a = *(const float4*)&src[base];
        float4 c = *(const float4*)&src[base + 4];
        float xs[8] = {a.x, a.y, a.z, a.w, c.x, c.y, c.z, c.w};
        f16x8 hi, lo;
#pragma unroll
        for (int e = 0; e < 8; ++e) {
            f16 hh = (f16)xs[e];
            hi[e] = hh;
            lo[e] = (f16)(xs[e] - (float)hh);
        }
        *(f16x8*)&dh[base] = hi;
        *(f16x8*)&dl[base] = lo;
    }
}

// ---------------------------------------------------------------------------
// Fused projection. Grid (BT/128, EE/64, 2), block 256 (4 waves).
// z=0: Q from (qAhi,qAlo); z=1: K' and V from (kvAhi,kvAlo).
// Tile 128x64, BK=32, dbuf LDS + reg prefetch.
// ---------------------------------------------------------------------------
__global__ __launch_bounds__(256) void proj_k(
    const f16* __restrict__ qAhi, const f16* __restrict__ qAlo,
    const f16* __restrict__ kvAhi, const f16* __restrict__ kvAlo,
    const f16* __restrict__ wqh, const f16* __restrict__ wql,
    const f16* __restrict__ wkh, const f16* __restrict__ wkl,
    const f16* __restrict__ wvh,
    f16* __restrict__ qhi, f16* __restrict__ qlo,
    f16* __restrict__ khi, f16* __restrict__ klo, f16* __restrict__ vT) {
    __shared__ __align__(16) f16 Ah_s[2][128][40];
    __shared__ __align__(16) f16 Al_s[2][128][40];
    __shared__ __align__(16) f16 Wh_s[2][64][40];
    __shared__ __align__(16) f16 Wl_s[2][64][40];
    __shared__ __align__(16) f16 Wv_s[2][64][40];
    f16 (*Ep)[136] = reinterpret_cast<f16(*)[136]>(&Ah_s[0][0][0]);

    const int t = threadIdx.x;
    const int w = t >> 6, l = t & 63;
    const int wm = w >> 1, wn = w & 1;
    const int fr = l & 15, fc = l >> 4;
    const int m0b = blockIdx.x * 128;
    const int n0b = blockIdx.y * 64;
    const int z   = blockIdx.z;
    const int ar = t >> 1, ak = t & 1;
    const int wr = t >> 2, wc = t & 3;

    const f16* AH = z ? kvAhi : qAhi;
    const f16* AL = z ? kvAlo : qAlo;
    const f16* WH = z ? wkh : wqh;
    const f16* WL = z ? wkl : wql;

    f32x4 accK[4][2], accV[4][2];
#pragma unroll
    for (int i = 0; i < 4; ++i)
#pragma unroll
        for (int j = 0; j < 2; ++j) {
            accK[i][j] = f32x4{0.f, 0.f, 0.f, 0.f};
            accV[i][j] = f32x4{0.f, 0.f, 0.f, 0.f};
        }

    f16x8 ah8[2], al8[2], wh8, wl8, wv8;

    auto loadAB = [&](int k0) {
        size_t aoff = (size_t)(m0b + ar) * EE + k0 + ak * 16;
        ah8[0] = *(const f16x8*)&AH[aoff];
        ah8[1] = *(const f16x8*)&AH[aoff + 8];
        al8[0] = *(const f16x8*)&AL[aoff];
        al8[1] = *(const f16x8*)&AL[aoff + 8];
        size_t woff = (size_t)(n0b + wr) * EE + k0 + wc * 8;
        wh8 = *(const f16x8*)&WH[woff];
        wl8 = *(const f16x8*)&WL[woff];
        if (z) wv8 = *(const f16x8*)&wvh[woff];
    };
    auto stage = [&](int bf) {
        *(f16x8*)&Ah_s[bf][ar][ak * 16]     = ah8[0];
        *(f16x8*)&Ah_s[bf][ar][ak * 16 + 8] = ah8[1];
        *(f16x8*)&Al_s[bf][ar][ak * 16]     = al8[0];
        *(f16x8*)&Al_s[bf][ar][ak * 16 + 8] = al8[1];
        *(f16x8*)&Wh_s[bf][wr][wc * 8] = wh8;
        *(f16x8*)&Wl_s[bf][wr][wc * 8] = wl8;
        if (z) *(f16x8*)&Wv_s[bf][wr][wc * 8] = wv8;
    };

    loadAB(0);
    stage(0);
    __syncthreads();
    int cur = 0;
    for (int ks = 0; ks < 16; ++ks) {
        if (ks < 15) loadAB((ks + 1) * 32);
        f16x8 Ahf[4], Alf[4], Bh[2], Bl[2], Bv[2];
#pragma unroll
        for (int mi = 0; mi < 4; ++mi) {
            Ahf[mi] = *(const f16x8*)&Ah_s[cur][wm * 64 + mi * 16 + fr][fc * 8];
            Alf[mi] = *(const f16x8*)&Al_s[cur][wm * 64 + mi * 16 + fr][fc * 8];
        }
#pragma unroll
        for (int nj = 0; nj < 2; ++nj) {
            Bh[nj] = *(const f16x8*)&Wh_s[cur][wn * 32 + nj * 16 + fr][fc * 8];
            Bl[nj] = *(const f16x8*)&Wl_s[cur][wn * 32 + nj * 16 + fr][fc * 8];
            if (z) Bv[nj] = *(const f16x8*)&Wv_s[cur][wn * 32 + nj * 16 + fr][fc * 8];
        }
        __builtin_amdgcn_s_setprio(1);
#pragma unroll
        for (int mi = 0; mi < 4; ++mi)
#pragma unroll
            for (int nj = 0; nj < 2; ++nj) {
                accK[mi][nj] = __builtin_amdgcn_mfma_f32_16x16x32_f16(
                    Ahf[mi], Bh[nj], accK[mi][nj], 0, 0, 0);
                accK[mi][nj] = __builtin_amdgcn_mfma_f32_16x16x32_f16(
                    Ahf[mi], Bl[nj], accK[mi][nj], 0, 0, 0);
                accK[mi][nj] = __builtin_amdgcn_mfma_f32_16x16x32_f16(
                    Alf[mi], Bh[nj], accK[mi][nj], 0, 0, 0);
                if (z)
                    accV[mi][nj] = __builtin_amdgcn_mfma_f32_16x16x32_f16(
                        Ahf[mi], Bv[nj], accV[mi][nj], 0, 0, 0);
            }
        __builtin_amdgcn_s_setprio(0);
        if (ks < 15) stage(cur ^ 1);
        __syncthreads();
        cur ^= 1;
    }

    // ---- epilogue (Ep aliases dead LDS) ----
    f16* dsthi = z ? khi : qhi;
    f16* dstlo = z ? klo : qlo;
#pragma unroll
    for (int mi = 0; mi < 4; ++mi)
#pragma unroll
        for (int nj = 0; nj < 2; ++nj)
#pragma unroll
            for (int r = 0; r < 4; ++r)
                Ep[wn * 32 + nj * 16 + fr][wm * 64 + mi * 16 + fc * 4 + r] =
                    (f16)accK[mi][nj][r];
    __syncthreads();
#pragma unroll
    for (int i = 0; i < 4; ++i) {
        int task = t * 4 + i;
        int mr = task >> 3, h = task & 7;
        f16x8 v;
#pragma unroll
        for (int d = 0; d < 8; ++d) v[d] = Ep[8 * d + h][mr];
        *(f16x8*)&dsthi[((size_t)h * BT + m0b + mr) * DD + (n0b >> 3)] = v;
    }
    __syncthreads();
#pragma unroll
    for (int mi = 0; mi < 4; ++mi)
#pragma unroll
        for (int nj = 0; nj < 2; ++nj)
#pragma unroll
            for (int r = 0; r < 4; ++r) {
                float x = accK[mi][nj][r];
                f16 hh = (f16)x;
                Ep[wn * 32 + nj * 16 + fr][wm * 64 + mi * 16 + fc * 4 + r] =
                    (f16)(x - (float)hh);
            }
    __syncthreads();
#pragma unroll
    for (int i = 0; i < 4; ++i) {
        int task = t * 4 + i;
        int mr = task >> 3, h = task & 7;
        f16x8 v;
#pragma unroll
        for (int d = 0; d < 8; ++d) v[d] = Ep[8 * d + h][mr];
        *(f16x8*)&dstlo[((size_t)h * BT + m0b + mr) * DD + (n0b >> 3)] = v;
    }
    if (z) {
        __syncthreads();
#pragma unroll
        for (int mi = 0; mi < 4; ++mi)
#pragma unroll
            for (int nj = 0; nj < 2; ++nj)
#pragma unroll
                for (int r = 0; r < 4; ++r)
                    Ep[wn * 32 + nj * 16 + fr][wm * 64 + mi * 16 + fc * 4 + r] =
                        (f16)accV[mi][nj][r];
        __syncthreads();
#pragma unroll
        for (int i = 0; i < 4; ++i) {
            int task = t * 4 + i;           // (nn 0..63, mg 0..15)
            int mg = task & 15, nn = task >> 4;
            int h = nn & 7, dl = nn >> 3;
            f16x8 v = *(const f16x8*)&Ep[nn][mg * 8];
            *(f16x8*)&vT[((size_t)(h * DD + (n0b >> 3) + dl)) * BT +
                         m0b + mg * 8] = v;
        }
    }
}

// ---------------------------------------------------------------------------
// Output GEMM: out = ctx(f16) @ Wo (f16) -> fp32. Tile 64x64, BK=64.
// ---------------------------------------------------------------------------
__global__ __launch_bounds__(256) void outmm_k(const f16* __restrict__ Af,
                                               const f16* __restrict__ WThi,
                                               float* __restrict__ out) {
    __shared__ __align__(16) f16 Ah_s[2][64][72];
    __shared__ __align__(16) f16 Wh_s[2][64][72];

    const int t = threadIdx.x;
    const int w = t >> 6, l = t & 63;
    const int wm = w >> 1, wn = w & 1;
    const int fr = l & 15, fc = l >> 4;
    const int m0b = blockIdx.x * 64;
    const int n0b = blockIdx.y * 64;
    const int sr = t >> 2, sch = t & 3;

    f32x4 acc[2][2];
#pragma unroll
    for (int i = 0; i < 2; ++i)
#pragma unroll
        for (int j = 0; j < 2; ++j) acc[i][j] = f32x4{0.f, 0.f, 0.f, 0.f};

    f16x8 af[2], wf[2];
    auto loadAB = [&](int k0) {
#pragma unroll
        for (int i = 0; i < 2; ++i) {
            af[i] = *(const f16x8*)&Af[(size_t)(m0b + sr) * EE + k0 + sch * 16 + i * 8];
            wf[i] = *(const f16x8*)&WThi[(size_t)(n0b + sr) * EE + k0 + sch * 16 + i * 8];
        }
    };
    auto stage = [&](int bf) {
#pragma unroll
        for (int i = 0; i < 2; ++i) {
            *(f16x8*)&Ah_s[bf][sr][sch * 16 + i * 8] = af[i];
            *(f16x8*)&Wh_s[bf][sr][sch * 16 + i * 8] = wf[i];
        }
    };

    loadAB(0);
    stage(0);
    __syncthreads();
    int cur = 0;
    for (int ks = 0; ks < 8; ++ks) {
        if (ks < 7) loadAB((ks + 1) * 64);
        f16x8 Ahf[2][2], Bhf[2][2];
#pragma unroll
        for (int mi = 0; mi < 2; ++mi)
#pragma unroll
            for (int kb = 0; kb < 2; ++kb)
                Ahf[mi][kb] =
                    *(const f16x8*)&Ah_s[cur][wm * 32 + mi * 16 + fr][kb * 32 + fc * 8];
#pragma unroll
        for (int nj = 0; nj < 2; ++nj)
#pragma unroll
            for (int kb = 0; kb < 2; ++kb)
                Bhf[nj][kb] =
                    *(const f16x8*)&Wh_s[cur][wn * 32 + nj * 16 + fr][kb * 32 + fc * 8];
        __builtin_amdgcn_s_setprio(1);
#pragma unroll
        for (int mi = 0; mi < 2; ++mi)
#pragma unroll
            for (int nj = 0; nj < 2; ++nj)
#pragma unroll
                for (int kb = 0; kb < 2; ++kb)
                    acc[mi][nj] = __builtin_amdgcn_mfma_f32_16x16x32_f16(
                        Ahf[mi][kb], Bhf[nj][kb], acc[mi][nj], 0, 0, 0);
        __builtin_amdgcn_s_setprio(0);
        if (ks < 7) stage(cur ^ 1);
        __syncthreads();
        cur ^= 1;
    }

#pragma unroll
    for (int mi = 0; mi < 2; ++mi)
#pragma unroll
        for (int nj = 0; nj < 2; ++nj)
#pragma unroll
            for (int r = 0; r < 4; ++r)
                out[(size_t)(m0b + wm * 32 + mi * 16 + fc * 4 + r) * EE +
                    n0b + wn * 32 + nj * 16 + fr] = acc[mi][nj][r];
}

// ---------------------------------------------------------------------------
// Split-KV flash attention partial pass. Grid 1024 (XCD-swizzled):
// (bx 0..15, s 0..1, h 0..7, b 0..3). Block = 4 waves x 16 q rows; keys
// [s*512, s*512+512) in 8 tiles of 64. Writes unnormalized O (f32) + (m,l).
// ---------------------------------------------------------------------------
__global__ __launch_bounds__(256) void attn_part_k(const f16* __restrict__ qhiP,
    const f16* __restrict__ qloP, const f16* __restrict__ khiP,
    const f16* __restrict__ kloP, const f16* __restrict__ vTP,
    float* __restrict__ Opart, float* __restrict__ mlP) {
    __shared__ __align__(16) f16 Khi[2][64][64];   // XOR-swizzled 16B chunks
    __shared__ __align__(16) f16 Klo[2][64][64];
    __shared__ __align__(16) f16 Pl[4][16][72];    // per-wave P[q][key]

    const int bid = blockIdx.x;                 // 0..1023
    const int swz = (bid & 7) * 128 + (bid >> 3);
    const int bx = swz & 15;
    const int s  = (swz >> 4) & 1;
    const int h  = (swz >> 5) & 7;
    const int b  = swz >> 8;

    const int t  = threadIdx.x;
    const int w  = t >> 6;
    const int l  = t & 63;
    const int lg = l >> 4;
    const int lq = l & 15;
    const int q0 = bx * 64 + w * 16;
    const size_t plane = ((size_t)h * BT + (size_t)b * TT) * DD;

    f16x8 Qhi[2], Qlo[2];
#pragma unroll
    for (int kf = 0; kf < 2; ++kf) {
        size_t qo = plane + (size_t)(q0 + lq) * DD + kf * 32 + lg * 8;
        Qhi[kf] = *(const f16x8*)&qhiP[qo];
        Qlo[kf] = *(const f16x8*)&qloP[qo];
    }
    const f16* vbase = vTP + ((size_t)h * DD + lq) * BT + (size_t)b * TT + lg * 8;

    f32x4 Oacc[4];
#pragma unroll
    for (int i = 0; i < 4; ++i) Oacc[i] = f32x4{0.f, 0.f, 0.f, 0.f};
    float m = -1e30f, lsum = 0.f;

    const int sr = t >> 2, sch = t & 3;
    f16x8 kh[2], kl[2];

    auto loadK = [&](int kt0) {
        size_t off = plane + (size_t)(kt0 + sr) * DD + sch * 16;
        kh[0] = *(const f16x8*)&khiP[off];
        kh[1] = *(const f16x8*)&khiP[off + 8];
        kl[0] = *(const f16x8*)&kloP[off];
        kl[1] = *(const f16x8*)&kloP[off + 8];
    };
    auto stageK = [&](int bf) {
#pragma unroll
        for (int i = 0; i < 2; ++i) {
            int chunk = sch * 2 + i;
            int dsw = chunk ^ (sr & 7);
            *(f16x8*)&Khi[bf][sr][dsw * 8] = kh[i];
            *(f16x8*)&Klo[bf][sr][dsw * 8] = kl[i];
        }
    };

    const int k_beg = s * 512, k_end = k_beg + 512;
    loadK(k_beg);
    stageK(0);
    __syncthreads();
    int cur = 0;

    for (int kt0 = k_beg; kt0 < k_end; kt0 += 64) {
        // ---- V fragments for THIS tile (contiguous 16B L2 reads) ----
        f16x8 bv[2][4];
#pragma unroll
        for (int kf = 0; kf < 2; ++kf)
#pragma unroll
            for (int dvt = 0; dvt < 4; ++dvt)
                bv[kf][dvt] = *(const f16x8*)&vbase[(size_t)dvt * 16 * BT +
                                                    kt0 + kf * 32];
        if (kt0 + 64 < k_end) loadK(kt0 + 64);

        // ---- QK^T (swapped): S^T[key][q], 3-product split fp16 ----
        f32x4 Sc[4];
        __builtin_amdgcn_s_setprio(1);
#pragma unroll
        for (int kt = 0; kt < 4; ++kt) {
            f32x4 c = f32x4{0.f, 0.f, 0.f, 0.f};
            int keyr = kt * 16 + lq;
#pragma unroll
            for (int kf = 0; kf < 2; ++kf) {
                int dblk = kf * 4 + lg;
                int sw = dblk ^ (keyr & 7);
                f16x8 ahi = *(const f16x8*)&Khi[cur][keyr][sw * 8];
                f16x8 alo = *(const f16x8*)&Klo[cur][keyr][sw * 8];
                c = __builtin_amdgcn_mfma_f32_16x16x32_f16(ahi, Qhi[kf], c, 0, 0, 0);
                c = __builtin_amdgcn_mfma_f32_16x16x32_f16(ahi, Qlo[kf], c, 0, 0, 0);
                c = __builtin_amdgcn_mfma_f32_16x16x32_f16(alo, Qhi[kf], c, 0, 0, 0);
            }
            Sc[kt] = c;
        }
        __builtin_amdgcn_s_setprio(0);

        // ---- online softmax for q-row lq ----
        float sv[16];
#pragma unroll
        for (int kt = 0; kt < 4; ++kt)
#pragma unroll
            for (int r = 0; r < 4; ++r) sv[kt * 4 + r] = Sc[kt][r];
        float tm = sv[0];
#pragma unroll
        for (int i = 1; i < 16; ++i) tm = fmaxf(tm, sv[i]);
        tm = fmaxf(tm, __shfl_xor(tm, 16));
        tm = fmaxf(tm, __shfl_xor(tm, 32));

        bool skip = __all(tm <= m + 8.0f);
        float Mn = m, corr = 1.0f;
        if (!skip) {
            Mn = fmaxf(m, tm);
            corr = __expf(m - Mn);
        }
        float ps = 0.f;
        f16 ph[16];
#pragma unroll
        for (int i = 0; i < 16; ++i) {
            float p = __expf(sv[i] - Mn);
            ps += p;
            ph[i] = (f16)p;
        }
        ps += __shfl_xor(ps, 16);
        ps += __shfl_xor(ps, 32);
        if (skip) {
            lsum += ps;
        } else {
            lsum = lsum * corr + ps;
            m = Mn;
        }

        // ---- write P (fp16 packed pairs) ----
#pragma unroll
        for (int kt = 0; kt < 4; ++kt)
#pragma unroll
            for (int rp = 0; rp < 4; rp += 2) {
                union { f16 h; unsigned short u; } u0, u1;
                u0.h = ph[kt * 4 + rp]; u1.h = ph[kt * 4 + rp + 1];
                unsigned int pk = ((unsigned int)u1.u << 16) | u0.u;
                *(unsigned int*)&Pl[w][lq][kt * 16 + lg * 4 + rp] = pk;
            }

        if (!skip) {
            float cq[4];
#pragma unroll
            for (int r = 0; r < 4; ++r) cq[r] = __shfl(corr, lg * 4 + r);
#pragma unroll
            for (int dvt = 0; dvt < 4; ++dvt)
#pragma unroll
                for (int r = 0; r < 4; ++r) Oacc[dvt][r] *= cq[r];
        }

        // ---- PV: O += P @ V ----
        __builtin_amdgcn_s_setprio(1);
#pragma unroll
        for (int kf = 0; kf < 2; ++kf) {
            f16x8 pa = *(const f16x8*)&Pl[w][lq][kf * 32 + lg * 8];
#pragma unroll
            for (int dvt = 0; dvt < 4; ++dvt)
                Oacc[dvt] = __builtin_amdgcn_mfma_f32_16x16x32_f16(
                    pa, bv[kf][dvt], Oacc[dvt], 0, 0, 0);
        }
        __builtin_amdgcn_s_setprio(0);

        if (kt0 + 64 < k_end) stageK(cur ^ 1);
        __syncthreads();
        cur ^= 1;
    }

    // ---- store unnormalized partials ----
    const size_t rowbase = (size_t)(s * HH + h) * BT + (size_t)b * TT + q0;
    if (lg == 0) {
        mlP[(rowbase + lq) * 2]     = m;
        mlP[(rowbase + lq) * 2 + 1] = lsum;
    }
#pragma unroll
    for (int r = 0; r < 4; ++r) {
        float* orow = Opart + (rowbase + lg * 4 + r) * DD;
#pragma unroll
        for (int dvt = 0; dvt < 4; ++dvt)
            orow[dvt * 16 + lq] = Oacc[dvt][r];
    }
}

// ---------------------------------------------------------------------------
// Combine S=2 partials -> ctx f16 [BT][512] (merged heads).
// task = (h, gq, d8): 8 * 4096 * 8 = 262144 threads.
// ---------------------------------------------------------------------------
__global__ __launch_bounds__(256) void comb_k(const float* __restrict__ Op,
                                              const float* __restrict__ ml,
                                              f16* __restrict__ ctx) {
    int task = blockIdx.x * 256 + threadIdx.x;
    int d8 = task & 7;
    int gq = (task >> 3) & (BT - 1);
    int h  = task >> 15;
    size_t r1 = (size_t)h * BT + gq;
    size_t r2 = (size_t)(HH + h) * BT + gq;
    float m1 = ml[r1 * 2], l1 = ml[r1 * 2 + 1];
    float m2 = ml[r2 * 2], l2 = ml[r2 * 2 + 1];
    float M = fmaxf(m1, m2);
    float w1 = __expf(m1 - M), w2 = __expf(m2 - M);
    float inv = 1.0f / (l1 * w1 + l2 * w2);
    w1 *= inv; w2 *= inv;
    const float4* o1 = (const float4*)&Op[r1 * DD + d8 * 8];
    const float4* o2 = (const float4*)&Op[r2 * DD + d8 * 8];
    float4 a1 = o1[0], b1 = o1[1];
    float4 a2 = o2[0], b2 = o2[1];
    f16x8 o;
    o[0] = (f16)(a1.x * w1 + a2.x * w2);
    o[1] = (f16)(a1.y * w1 + a2.y * w2);
    o[2] = (f16)(a1.z * w1 + a2.z * w2);
    o[3] = (f16)(a1.w * w1 + a2.w * w2);
    o[4] = (f16)(b1.x * w1 + b2.x * w2);
    o[5] = (f16)(b1.y * w1 + b2.y * w2);
    o[6] = (f16)(b1.z * w1 + b2.z * w2);
    o[7] = (f16)(b1.w * w1 + b2.w * w2);
    *(f16x8*)&ctx[(size_t)gq * EE + h * DD + d8 * 8] = o;
}

// ---------------------------------------------------------------------------
extern "C" void kernel_launch(void* const* d_in, const int* in_sizes, int n_in,
                              void* d_out, int out_size, void* d_ws, size_t ws_size,
                              hipStream_t stream) {
    const float* q  = (const float*)d_in[0];
    const float* kv = (const float*)d_in[1];
    const float* Wq = (const float*)d_in[2];
    const float* Wk = (const float*)d_in[3];
    const float* Wv = (const float*)d_in[4];
    const float* Wo = (const float*)d_in[5];
    float* out = (float*)d_out;

    f16* ws = (f16*)d_ws;
    const size_t PL  = (size_t)HH * BT * DD;   // 2,097,152 f16 per plane
    const size_t WPL = (size_t)EE * EE;
    f16* qhi   = ws + 0 * PL;
    f16* qlo   = ws + 1 * PL;
    f16* khi   = ws + 2 * PL;
    f16* klo   = ws + 3 * PL;
    f16* vT    = ws + 4 * PL;      // [H][64][BT]
    f16* ctx   = ws + 5 * PL;      // [BT][512]
    f16* qAhi  = ws + 6 * PL;
    f16* qAlo  = ws + 7 * PL;
    f16* kvAhi = ws + 8 * PL;
    f16* kvAlo = ws + 9 * PL;
    f16* wqh = ws + 10 * PL;
    f16* wql = wqh + 1 * WPL;
    f16* wkh = wqh + 2 * WPL;
    f16* wkl = wqh + 3 * WPL;
    f16* wvh = wqh + 4 * WPL;
    f16* woh = wqh + 5 * WPL;
    float* Opart = (float*)(wqh + 6 * WPL);        // [2*H][BT][64] f32 = 16 MB
    float* mlP   = Opart + (size_t)2 * HH * BT * DD; // [2*H][BT][2] f32

    prep_k<<<dim3(1024, 6), dim3(256), 0, stream>>>(
        q, kv, Wq, Wk, Wv, Wo, wqh, wql, wkh, wkl, wvh, woh,
        qAhi, qAlo, kvAhi, kvAlo);

    proj_k<<<dim3(BT / 128, EE / 64, 2), dim3(256), 0, stream>>>(
        qAhi, qAlo, kvAhi, kvAlo, wqh, wql, wkh, wkl, wvh,
        qhi, qlo, khi, klo, vT);

    attn_part_k<<<dim3(1024), dim3(256), 0, stream>>>(
        qhi, qlo, khi, klo, vT, Opart, mlP);

    comb_k<<<dim3(1024), dim3(256), 0, stream>>>(Opart, mlP, ctx);

    outmm_k<<<dim3(BT / 64, EE / 64), dim3(256), 0, stream>>>(ctx, woh, out);
}

// Round 9
// 77.082 us; speedup vs baseline: 1.2364x; 1.2364x over previous
//
#include <hip/hip_runtime.h>
#include <math.h>

#define BB 4
#define TT 1024
#define EE 512
#define HH 8
#define DD 64
#define BT (BB * TT)   // 4096

typedef _Float16 f16;
typedef __attribute__((ext_vector_type(8))) _Float16 f16x8;
typedef __attribute__((ext_vector_type(4))) float f32x4;

// ---------------------------------------------------------------------------
// Prep: y=0..3 weight planes (transposed f16), y=4/5 split q/kv into hi+lo
// f16 planes [BT][512]. Grid (1024, 6).
// ---------------------------------------------------------------------------
__global__ __launch_bounds__(256) void prep_k(
    const float* __restrict__ q, const float* __restrict__ kv,
    const float* __restrict__ Wq, const float* __restrict__ Wk,
    const float* __restrict__ Wv, const float* __restrict__ Wo,
    f16* __restrict__ wqh, f16* __restrict__ wql,
    f16* __restrict__ wkh, f16* __restrict__ wkl,
    f16* __restrict__ wvh, f16* __restrict__ woh,
    f16* __restrict__ qAhi, f16* __restrict__ qAlo,
    f16* __restrict__ kvAhi, f16* __restrict__ kvAlo) {
    const int t = threadIdx.x;
    const int y = blockIdx.y;
    if (y < 4) {
        int idx = blockIdx.x * 256 + t;        // 512*512 elems
        int k = idx & (EE - 1);
        int n = idx >> 9;
        if (y == 0) {
            float v = Wq[k * EE + n] * 512.0f; // fold dk*D scale (exact pow2)
            f16 hi = (f16)v;
            wqh[n * EE + k] = hi;
            wql[n * EE + k] = (f16)(v - (float)hi);
        } else if (y == 1) {
            int d = n >> 3, h = n & 7;
            int sn = (((DD - d) & (DD - 1)) << 3) | h;  // K'[.,d]=K[.,(D-d)%D]
            float v = Wk[k * EE + sn];
            f16 hi = (f16)v;
            wkh[n * EE + k] = hi;
            wkl[n * EE + k] = (f16)(v - (float)hi);
        } else if (y == 2) {
            wvh[n * EE + k] = (f16)Wv[k * EE + n];
        } else {
            woh[n * EE + k] = (f16)Wo[k * EE + n];
        }
    } else {
        const float* src = (y == 4) ? q : kv;
        f16* dh = (y == 4) ? qAhi : kvAhi;
        f16* dl = (y == 4) ? qAlo : kvAlo;
        int base = (blockIdx.x * 256 + t) * 8;
        float4 a = *(const float4*)&src[base];
        float4 c = *(const float4*)&src[base + 4];
        float xs[8] = {a.x, a.y, a.z, a.w, c.x, c.y, c.z, c.w};
        f16x8 hi, lo;
#pragma unroll
        for (int e = 0; e < 8; ++e) {
            f16 hh = (f16)xs[e];
            hi[e] = hh;
            lo[e] = (f16)(xs[e] - (float)hh);
        }
        *(f16x8*)&dh[base] = hi;
        *(f16x8*)&dl[base] = lo;
    }
}

// ---------------------------------------------------------------------------
// Fused projection. Grid (BT/128, EE/64, 2), block 256 (4 waves).
// z=0: Q from (qAhi,qAlo); z=1: K' and V from (kvAhi,kvAlo).
// Tile 128x64, BK=32, dbuf LDS + reg prefetch. V stored fragment-packed:
// vP[h][tile64][kf][dvt][lane][8keys] so attn PV loads are lane-contiguous.
// ---------------------------------------------------------------------------
__global__ __launch_bounds__(256) void proj_k(
    const f16* __restrict__ qAhi, const f16* __restrict__ qAlo,
    const f16* __restrict__ kvAhi, const f16* __restrict__ kvAlo,
    const f16* __restrict__ wqh, const f16* __restrict__ wql,
    const f16* __restrict__ wkh, const f16* __restrict__ wkl,
    const f16* __restrict__ wvh,
    f16* __restrict__ qhi, f16* __restrict__ qlo,
    f16* __restrict__ khi, f16* __restrict__ klo, f16* __restrict__ vP) {
    __shared__ __align__(16) f16 Ah_s[2][128][40];
    __shared__ __align__(16) f16 Al_s[2][128][40];
    __shared__ __align__(16) f16 Wh_s[2][64][40];
    __shared__ __align__(16) f16 Wl_s[2][64][40];
    __shared__ __align__(16) f16 Wv_s[2][64][40];
    f16 (*Ep)[136] = reinterpret_cast<f16(*)[136]>(&Ah_s[0][0][0]);

    const int t = threadIdx.x;
    const int w = t >> 6, l = t & 63;
    const int wm = w >> 1, wn = w & 1;
    const int fr = l & 15, fc = l >> 4;
    const int m0b = blockIdx.x * 128;
    const int n0b = blockIdx.y * 64;
    const int z   = blockIdx.z;
    const int ar = t >> 1, ak = t & 1;
    const int wr = t >> 2, wc = t & 3;

    const f16* AH = z ? kvAhi : qAhi;
    const f16* AL = z ? kvAlo : qAlo;
    const f16* WH = z ? wkh : wqh;
    const f16* WL = z ? wkl : wql;

    f32x4 accK[4][2], accV[4][2];
#pragma unroll
    for (int i = 0; i < 4; ++i)
#pragma unroll
        for (int j = 0; j < 2; ++j) {
            accK[i][j] = f32x4{0.f, 0.f, 0.f, 0.f};
            accV[i][j] = f32x4{0.f, 0.f, 0.f, 0.f};
        }

    f16x8 ah8[2], al8[2], wh8, wl8, wv8;

    auto loadAB = [&](int k0) {
        size_t aoff = (size_t)(m0b + ar) * EE + k0 + ak * 16;
        ah8[0] = *(const f16x8*)&AH[aoff];
        ah8[1] = *(const f16x8*)&AH[aoff + 8];
        al8[0] = *(const f16x8*)&AL[aoff];
        al8[1] = *(const f16x8*)&AL[aoff + 8];
        size_t woff = (size_t)(n0b + wr) * EE + k0 + wc * 8;
        wh8 = *(const f16x8*)&WH[woff];
        wl8 = *(const f16x8*)&WL[woff];
        if (z) wv8 = *(const f16x8*)&wvh[woff];
    };
    auto stage = [&](int bf) {
        *(f16x8*)&Ah_s[bf][ar][ak * 16]     = ah8[0];
        *(f16x8*)&Ah_s[bf][ar][ak * 16 + 8] = ah8[1];
        *(f16x8*)&Al_s[bf][ar][ak * 16]     = al8[0];
        *(f16x8*)&Al_s[bf][ar][ak * 16 + 8] = al8[1];
        *(f16x8*)&Wh_s[bf][wr][wc * 8] = wh8;
        *(f16x8*)&Wl_s[bf][wr][wc * 8] = wl8;
        if (z) *(f16x8*)&Wv_s[bf][wr][wc * 8] = wv8;
    };

    loadAB(0);
    stage(0);
    __syncthreads();
    int cur = 0;
    for (int ks = 0; ks < 16; ++ks) {
        if (ks < 15) loadAB((ks + 1) * 32);
        f16x8 Ahf[4], Alf[4], Bh[2], Bl[2], Bv[2];
#pragma unroll
        for (int mi = 0; mi < 4; ++mi) {
            Ahf[mi] = *(const f16x8*)&Ah_s[cur][wm * 64 + mi * 16 + fr][fc * 8];
            Alf[mi] = *(const f16x8*)&Al_s[cur][wm * 64 + mi * 16 + fr][fc * 8];
        }
#pragma unroll
        for (int nj = 0; nj < 2; ++nj) {
            Bh[nj] = *(const f16x8*)&Wh_s[cur][wn * 32 + nj * 16 + fr][fc * 8];
            Bl[nj] = *(const f16x8*)&Wl_s[cur][wn * 32 + nj * 16 + fr][fc * 8];
            if (z) Bv[nj] = *(const f16x8*)&Wv_s[cur][wn * 32 + nj * 16 + fr][fc * 8];
        }
        __builtin_amdgcn_s_setprio(1);
#pragma unroll
        for (int mi = 0; mi < 4; ++mi)
#pragma unroll
            for (int nj = 0; nj < 2; ++nj) {
                accK[mi][nj] = __builtin_amdgcn_mfma_f32_16x16x32_f16(
                    Ahf[mi], Bh[nj], accK[mi][nj], 0, 0, 0);
                accK[mi][nj] = __builtin_amdgcn_mfma_f32_16x16x32_f16(
                    Ahf[mi], Bl[nj], accK[mi][nj], 0, 0, 0);
                accK[mi][nj] = __builtin_amdgcn_mfma_f32_16x16x32_f16(
                    Alf[mi], Bh[nj], accK[mi][nj], 0, 0, 0);
                if (z)
                    accV[mi][nj] = __builtin_amdgcn_mfma_f32_16x16x32_f16(
                        Ahf[mi], Bv[nj], accV[mi][nj], 0, 0, 0);
            }
        __builtin_amdgcn_s_setprio(0);
        if (ks < 15) stage(cur ^ 1);
        __syncthreads();
        cur ^= 1;
    }

    // ---- epilogue (Ep aliases dead LDS) ----
    f16* dsthi = z ? khi : qhi;
    f16* dstlo = z ? klo : qlo;
#pragma unroll
    for (int mi = 0; mi < 4; ++mi)
#pragma unroll
        for (int nj = 0; nj < 2; ++nj)
#pragma unroll
            for (int r = 0; r < 4; ++r)
                Ep[wn * 32 + nj * 16 + fr][wm * 64 + mi * 16 + fc * 4 + r] =
                    (f16)accK[mi][nj][r];
    __syncthreads();
#pragma unroll
    for (int i = 0; i < 4; ++i) {
        int task = t * 4 + i;
        int mr = task >> 3, h = task & 7;
        f16x8 v;
#pragma unroll
        for (int d = 0; d < 8; ++d) v[d] = Ep[8 * d + h][mr];
        *(f16x8*)&dsthi[((size_t)h * BT + m0b + mr) * DD + (n0b >> 3)] = v;
    }
    __syncthreads();
#pragma unroll
    for (int mi = 0; mi < 4; ++mi)
#pragma unroll
        for (int nj = 0; nj < 2; ++nj)
#pragma unroll
            for (int r = 0; r < 4; ++r) {
                float x = accK[mi][nj][r];
                f16 hh = (f16)x;
                Ep[wn * 32 + nj * 16 + fr][wm * 64 + mi * 16 + fc * 4 + r] =
                    (f16)(x - (float)hh);
            }
    __syncthreads();
#pragma unroll
    for (int i = 0; i < 4; ++i) {
        int task = t * 4 + i;
        int mr = task >> 3, h = task & 7;
        f16x8 v;
#pragma unroll
        for (int d = 0; d < 8; ++d) v[d] = Ep[8 * d + h][mr];
        *(f16x8*)&dstlo[((size_t)h * BT + m0b + mr) * DD + (n0b >> 3)] = v;
    }
    if (z) {
        __syncthreads();
#pragma unroll
        for (int mi = 0; mi < 4; ++mi)
#pragma unroll
            for (int nj = 0; nj < 2; ++nj)
#pragma unroll
                for (int r = 0; r < 4; ++r)
                    Ep[wn * 32 + nj * 16 + fr][wm * 64 + mi * 16 + fc * 4 + r] =
                        (f16)accV[mi][nj][r];
        __syncthreads();
        // V fragment-packed store: vP[h][tile][kf][dvt][lane=lg*16+lq][e]
#pragma unroll
        for (int i = 0; i < 4; ++i) {
            int task = t * 4 + i;           // (nn 0..63, mg 0..15)
            int mg = task & 15, nn = task >> 4;
            int h = nn & 7, dl = nn >> 3;
            int d = (n0b >> 3) + dl;        // 0..63
            int koff = m0b + mg * 8;        // global key row (8-key run)
            int tile = koff >> 6;           // 0..63
            int kf   = (koff >> 5) & 1;
            int lg2  = (koff >> 3) & 3;
            int dvt  = d >> 4, lqd = d & 15;
            f16x8 v = *(const f16x8*)&Ep[nn][mg * 8];
            size_t off = (((((size_t)h * 64 + tile) * 2 + kf) * 4 + dvt) * 64 +
                          lg2 * 16 + lqd) * 8;
            *(f16x8*)&vP[off] = v;
        }
    }
}

// ---------------------------------------------------------------------------
// Output GEMM: out = ctx(f16) @ Wo (f16) -> fp32. Tile 64x64, BK=64.
// ---------------------------------------------------------------------------
__global__ __launch_bounds__(256) void outmm_k(const f16* __restrict__ Af,
                                               const f16* __restrict__ WThi,
                                               float* __restrict__ out) {
    __shared__ __align__(16) f16 Ah_s[2][64][72];
    __shared__ __align__(16) f16 Wh_s[2][64][72];

    const int t = threadIdx.x;
    const int w = t >> 6, l = t & 63;
    const int wm = w >> 1, wn = w & 1;
    const int fr = l & 15, fc = l >> 4;
    const int m0b = blockIdx.x * 64;
    const int n0b = blockIdx.y * 64;
    const int sr = t >> 2, sch = t & 3;

    f32x4 acc[2][2];
#pragma unroll
    for (int i = 0; i < 2; ++i)
#pragma unroll
        for (int j = 0; j < 2; ++j) acc[i][j] = f32x4{0.f, 0.f, 0.f, 0.f};

    f16x8 af[2], wf[2];
    auto loadAB = [&](int k0) {
#pragma unroll
        for (int i = 0; i < 2; ++i) {
            af[i] = *(const f16x8*)&Af[(size_t)(m0b + sr) * EE + k0 + sch * 16 + i * 8];
            wf[i] = *(const f16x8*)&WThi[(size_t)(n0b + sr) * EE + k0 + sch * 16 + i * 8];
        }
    };
    auto stage = [&](int bf) {
#pragma unroll
        for (int i = 0; i < 2; ++i) {
            *(f16x8*)&Ah_s[bf][sr][sch * 16 + i * 8] = af[i];
            *(f16x8*)&Wh_s[bf][sr][sch * 16 + i * 8] = wf[i];
        }
    };

    loadAB(0);
    stage(0);
    __syncthreads();
    int cur = 0;
    for (int ks = 0; ks < 8; ++ks) {
        if (ks < 7) loadAB((ks + 1) * 64);
        f16x8 Ahf[2][2], Bhf[2][2];
#pragma unroll
        for (int mi = 0; mi < 2; ++mi)
#pragma unroll
            for (int kb = 0; kb < 2; ++kb)
                Ahf[mi][kb] =
                    *(const f16x8*)&Ah_s[cur][wm * 32 + mi * 16 + fr][kb * 32 + fc * 8];
#pragma unroll
        for (int nj = 0; nj < 2; ++nj)
#pragma unroll
            for (int kb = 0; kb < 2; ++kb)
                Bhf[nj][kb] =
                    *(const f16x8*)&Wh_s[cur][wn * 32 + nj * 16 + fr][kb * 32 + fc * 8];
        __builtin_amdgcn_s_setprio(1);
#pragma unroll
        for (int mi = 0; mi < 2; ++mi)
#pragma unroll
            for (int nj = 0; nj < 2; ++nj)
#pragma unroll
                for (int kb = 0; kb < 2; ++kb)
                    acc[mi][nj] = __builtin_amdgcn_mfma_f32_16x16x32_f16(
                        Ahf[mi][kb], Bhf[nj][kb], acc[mi][nj], 0, 0, 0);
        __builtin_amdgcn_s_setprio(0);
        if (ks < 7) stage(cur ^ 1);
        __syncthreads();
        cur ^= 1;
    }

#pragma unroll
    for (int mi = 0; mi < 2; ++mi)
#pragma unroll
        for (int nj = 0; nj < 2; ++nj)
#pragma unroll
            for (int r = 0; r < 4; ++r)
                out[(size_t)(m0b + wm * 32 + mi * 16 + fc * 4 + r) * EE +
                    n0b + wn * 32 + nj * 16 + fr] = acc[mi][nj][r];
}

// ---------------------------------------------------------------------------
// MFMA flash attention: 64-key tiles, dbuf K in LDS, V fragments via
// coalesced packed loads (vP), defer-max, XCD-swizzled 1D grid (512).
// Block = 4 waves x 16 q rows.
// ---------------------------------------------------------------------------
__global__ __launch_bounds__(256) void attn_mfma_k(const f16* __restrict__ qhiP,
    const f16* __restrict__ qloP, const f16* __restrict__ khiP,
    const f16* __restrict__ kloP, const f16* __restrict__ vP,
    f16* __restrict__ ctx) {
    __shared__ __align__(16) f16 Khi[2][64][64];   // XOR-swizzled 16B chunks
    __shared__ __align__(16) f16 Klo[2][64][64];
    __shared__ __align__(16) f16 Pl[4][16][88];    // per-wave P[q][key]

    // XCD-aware decode: blocks sharing one (h,b)'s K/V land on one XCD
    const int bid = blockIdx.x;                 // 0..511
    const int swz = (bid & 7) * 64 + (bid >> 3);
    const int bx = swz & 15;
    const int h  = (swz >> 4) & 7;
    const int b  = swz >> 7;

    const int t  = threadIdx.x;
    const int w  = t >> 6;
    const int l  = t & 63;
    const int lg = l >> 4;
    const int lq = l & 15;
    const int q0 = bx * 64 + w * 16;
    const size_t plane = ((size_t)h * BT + (size_t)b * TT) * DD;

    f16x8 Qhi[2], Qlo[2];
#pragma unroll
    for (int kf = 0; kf < 2; ++kf) {
        size_t qo = plane + (size_t)(q0 + lq) * DD + kf * 32 + lg * 8;
        Qhi[kf] = *(const f16x8*)&qhiP[qo];
        Qlo[kf] = *(const f16x8*)&qloP[qo];
    }

    f32x4 Oacc[4];
#pragma unroll
    for (int i = 0; i < 4; ++i) Oacc[i] = f32x4{0.f, 0.f, 0.f, 0.f};
    float m = -1e30f, lsum = 0.f;

    const int sr = t >> 2, sch = t & 3;
    f16x8 kh[2], kl[2];

    auto loadK = [&](int kt0) {
        size_t off = plane + (size_t)(kt0 + sr) * DD + sch * 16;
        kh[0] = *(const f16x8*)&khiP[off];
        kh[1] = *(const f16x8*)&khiP[off + 8];
        kl[0] = *(const f16x8*)&kloP[off];
        kl[1] = *(const f16x8*)&kloP[off + 8];
    };
    auto stageK = [&](int bf) {
#pragma unroll
        for (int i = 0; i < 2; ++i) {
            int chunk = sch * 2 + i;
            int dsw = chunk ^ (sr & 7);
            *(f16x8*)&Khi[bf][sr][dsw * 8] = kh[i];
            *(f16x8*)&Klo[bf][sr][dsw * 8] = kl[i];
        }
    };

    loadK(0);
    stageK(0);
    __syncthreads();
    int cur = 0;

    for (int kt0 = 0; kt0 < TT; kt0 += 64) {
        // ---- V fragments: fully coalesced packed loads (1 KB/instr) ----
        const f16* tb = vP + ((size_t)h * 64 + ((b * TT + kt0) >> 6)) * 4096;
        f16x8 bv[2][4];
#pragma unroll
        for (int kf = 0; kf < 2; ++kf)
#pragma unroll
            for (int dvt = 0; dvt < 4; ++dvt)
                bv[kf][dvt] = *(const f16x8*)&tb[((kf * 4 + dvt) * 64 + l) * 8];
        if (kt0 + 64 < TT) loadK(kt0 + 64);

        // ---- QK^T (swapped): S^T[key][q], 3-product split fp16 ----
        f32x4 Sc[4];
        __builtin_amdgcn_s_setprio(1);
#pragma unroll
        for (int kt = 0; kt < 4; ++kt) {
            f32x4 c = f32x4{0.f, 0.f, 0.f, 0.f};
            int keyr = kt * 16 + lq;
#pragma unroll
            for (int kf = 0; kf < 2; ++kf) {
                int dblk = kf * 4 + lg;
                int sw = dblk ^ (keyr & 7);
                f16x8 ahi = *(const f16x8*)&Khi[cur][keyr][sw * 8];
                f16x8 alo = *(const f16x8*)&Klo[cur][keyr][sw * 8];
                c = __builtin_amdgcn_mfma_f32_16x16x32_f16(ahi, Qhi[kf], c, 0, 0, 0);
                c = __builtin_amdgcn_mfma_f32_16x16x32_f16(ahi, Qlo[kf], c, 0, 0, 0);
                c = __builtin_amdgcn_mfma_f32_16x16x32_f16(alo, Qhi[kf], c, 0, 0, 0);
            }
            Sc[kt] = c;
        }
        __builtin_amdgcn_s_setprio(0);

        // ---- online softmax for q-row lq (16 keys/lane) ----
        float sv[16];
#pragma unroll
        for (int kt = 0; kt < 4; ++kt)
#pragma unroll
            for (int r = 0; r < 4; ++r) sv[kt * 4 + r] = Sc[kt][r];
        float tm = sv[0];
#pragma unroll
        for (int i = 1; i < 16; ++i) tm = fmaxf(tm, sv[i]);
        tm = fmaxf(tm, __shfl_xor(tm, 16));
        tm = fmaxf(tm, __shfl_xor(tm, 32));

        bool skip = __all(tm <= m + 8.0f);
        float Mn = m, corr = 1.0f;
        if (!skip) {
            Mn = fmaxf(m, tm);
            corr = __expf(m - Mn);
        }
        float ps = 0.f;
        f16 ph[16];
#pragma unroll
        for (int i = 0; i < 16; ++i) {
            float p = __expf(sv[i] - Mn);
            ps += p;
            ph[i] = (f16)p;
        }
        ps += __shfl_xor(ps, 16);
        ps += __shfl_xor(ps, 32);
        if (skip) {
            lsum += ps;
        } else {
            lsum = lsum * corr + ps;
            m = Mn;
        }

        // ---- write P (fp16 packed pairs) ----
#pragma unroll
        for (int kt = 0; kt < 4; ++kt)
#pragma unroll
            for (int rp = 0; rp < 4; rp += 2) {
                union { f16 h; unsigned short u; } u0, u1;
                u0.h = ph[kt * 4 + rp]; u1.h = ph[kt * 4 + rp + 1];
                unsigned int pk = ((unsigned int)u1.u << 16) | u0.u;
                *(unsigned int*)&Pl[w][lq][kt * 16 + lg * 4 + rp] = pk;
            }

        if (!skip) {
            float cq[4];
#pragma unroll
            for (int r = 0; r < 4; ++r) cq[r] = __shfl(corr, lg * 4 + r);
#pragma unroll
            for (int dvt = 0; dvt < 4; ++dvt)
#pragma unroll
                for (int r = 0; r < 4; ++r) Oacc[dvt][r] *= cq[r];
        }

        // ---- PV: O += P @ V ----
        __builtin_amdgcn_s_setprio(1);
#pragma unroll
        for (int kf = 0; kf < 2; ++kf) {
            f16x8 pa = *(const f16x8*)&Pl[w][lq][kf * 32 + lg * 8];
#pragma unroll
            for (int dvt = 0; dvt < 4; ++dvt)
                Oacc[dvt] = __builtin_amdgcn_mfma_f32_16x16x32_f16(
                    pa, bv[kf][dvt], Oacc[dvt], 0, 0, 0);
        }
        __builtin_amdgcn_s_setprio(0);

        if (kt0 + 64 < TT) stageK(cur ^ 1);
        __syncthreads();
        cur ^= 1;
    }

    float linv = 1.0f / lsum;
    float lq4[4];
#pragma unroll
    for (int r = 0; r < 4; ++r) lq4[r] = __shfl(linv, lg * 4 + r);
#pragma unroll
    for (int r = 0; r < 4; ++r) {
        f16* crow = ctx + (size_t)(b * TT + q0 + lg * 4 + r) * EE + h * DD;
#pragma unroll
        for (int dvt = 0; dvt < 4; ++dvt)
            crow[dvt * 16 + lq] = (f16)(Oacc[dvt][r] * lq4[r]);
    }
}

// ---------------------------------------------------------------------------
extern "C" void kernel_launch(void* const* d_in, const int* in_sizes, int n_in,
                              void* d_out, int out_size, void* d_ws, size_t ws_size,
                              hipStream_t stream) {
    const float* q  = (const float*)d_in[0];
    const float* kv = (const float*)d_in[1];
    const float* Wq = (const float*)d_in[2];
    const float* Wk = (const float*)d_in[3];
    const float* Wv = (const float*)d_in[4];
    const float* Wo = (const float*)d_in[5];
    float* out = (float*)d_out;

    f16* ws = (f16*)d_ws;
    const size_t PL  = (size_t)HH * BT * DD;   // 2,097,152 f16 per plane
    const size_t WPL = (size_t)EE * EE;
    f16* qhi   = ws + 0 * PL;
    f16* qlo   = ws + 1 * PL;
    f16* khi   = ws + 2 * PL;
    f16* klo   = ws + 3 * PL;
    f16* vPck  = ws + 4 * PL;      // packed V fragments [H][64][2][4][64][8]
    f16* ctx   = ws + 5 * PL;      // [BT][512]
    f16* qAhi  = ws + 6 * PL;
    f16* qAlo  = ws + 7 * PL;
    f16* kvAhi = ws + 8 * PL;
    f16* kvAlo = ws + 9 * PL;
    f16* wqh = ws + 10 * PL;
    f16* wql = wqh + 1 * WPL;
    f16* wkh = wqh + 2 * WPL;
    f16* wkl = wqh + 3 * WPL;
    f16* wvh = wqh + 4 * WPL;
    f16* woh = wqh + 5 * WPL;

    prep_k<<<dim3(1024, 6), dim3(256), 0, stream>>>(
        q, kv, Wq, Wk, Wv, Wo, wqh, wql, wkh, wkl, wvh, woh,
        qAhi, qAlo, kvAhi, kvAlo);

    proj_k<<<dim3(BT / 128, EE / 64, 2), dim3(256), 0, stream>>>(
        qAhi, qAlo, kvAhi, kvAlo, wqh, wql, wkh, wkl, wvh,
        qhi, qlo, khi, klo, vPck);

    attn_mfma_k<<<dim3(512), dim3(256), 0, stream>>>(
        qhi, qlo, khi, klo, vPck, ctx);

    outmm_k<<<dim3(BT / 64, EE / 64), dim3(256), 0, stream>>>(ctx, woh, out);
}